// Round 3
// baseline (88.779 us; speedup 1.0000x reference)
//
#include <hip/hip_runtime.h>
#include <cmath>

namespace {
constexpr int HG = 48;
constexpr int NP = HG * HG;        // 2304
constexpr int CH = 16;
constexpr int WIN = 19;            // offsets -9..9
constexpr int WIN2 = WIN * WIN;    // 361
constexpr float RADIUS = 0.2f;
constexpr float EPS_H = 1e-6f;
constexpr float EPS_T = 1e-8f;
constexpr int KNOTS = 16;
constexpr int PPB = 4;             // points per block, one per (independent) wave
constexpr int NCAND = 6;           // ceil(361/64)
}

__device__ __forceinline__ float lin48(int t) {
    return (t == HG - 1) ? 1.0f : (float)t * (1.0f / 47.0f);
}

__device__ __forceinline__ float softplus_f(float v) {
    return fmaxf(v, 0.0f) + log1pf(expf(-fabsf(v)));
}

// wave-local fence: order LDS writes before subsequent reads (same wave only)
__device__ __forceinline__ void wave_lds_fence() {
    __asm__ volatile("s_waitcnt lgkmcnt(0)" ::: "memory");
}

__global__ __launch_bounds__(256)
void si_blocks_kernel(const float* __restrict__ x,
                      const float* __restrict__ phi_w1,
                      const float* __restrict__ phi_b1,
                      const float* __restrict__ phi_w2,
                      const float* __restrict__ phi_b2,
                      const float* __restrict__ h_w1,
                      const float* __restrict__ h_b1,
                      const float* __restrict__ h_w2,
                      const float* __restrict__ h_b2,
                      const float* __restrict__ S_m,
                      float* __restrict__ out)
{
    const int tid  = threadIdx.x;
    const int lane = tid & 63;
    const int wv   = tid >> 6;                 // wave slot == point slot
    const int i    = blockIdx.x * PPB + wv;    // 576 blocks * 4 = 2304
    const int ri   = i / HG;
    const int ci   = i - ri * HG;
    const float xi = lin48(ri);
    const float yi = lin48(ci);

    __shared__ float4 s_pq[PPB][32];           // (pre_k, wx_k, wy_k, w2_k) per wave
    __shared__ float  s_Sm[PPB][KNOTS];
    __shared__ float  s_w[PPB][WIN2];          // final weights (already / norm)

    // ---- per-wave setup (no cross-wave coupling, no __syncthreads anywhere)
    if (lane < 32) {
        const float pre = xi * phi_w1[lane] + yi * phi_w1[32 + lane] + phi_b1[lane];
        s_pq[wv][lane] = make_float4(pre, phi_w1[64 + lane], phi_w1[96 + lane],
                                     phi_w2[lane]);
    }
    if (lane < KNOTS) s_Sm[wv][lane] = S_m[lane];

    // h_net: both 32-lane halves compute identically; xor-reduce within halves
    float hval;
    {
        const int k = lane & 31;
        float t = fmaxf(xi * h_w1[k] + yi * h_w1[32 + k] + h_b1[k], 0.0f) * h_w2[k];
        #pragma unroll
        for (int m = 1; m < 32; m <<= 1) t += __shfl_xor(t, m, 64);
        hval = softplus_f(t + h_b2[0]) + EPS_H;
    }
    const float b2    = phi_b2[0];
    const float rhinv = 1.0f / hval;

    wave_lds_fence();

    // ---- Phase A: 361 candidates, 6 per lane
    float xjv[NCAND], yjv[NCAND], pw[NCAND], accp[NCAND];
    float cnt = 0.0f;

    #pragma unroll
    for (int s = 0; s < NCAND; ++s) {
        const int t  = lane + 64 * s;
        const int tt = (t < WIN2) ? t : 0;
        const int a  = tt / WIN;
        const int bb = tt - a * WIN;
        const int rj = ri + a - 9;
        const int cj = ci + bb - 9;
        const bool valid = (t < WIN2) &&
                           ((unsigned)rj < (unsigned)HG) &&
                           ((unsigned)cj < (unsigned)HG);
        const int rjc = min(max(rj, 0), HG - 1);
        const int cjc = min(max(cj, 0), HG - 1);
        const float xx = lin48(rjc);
        const float yy = lin48(cjc);
        const float dx = xi - xx;
        const float dy = yi - yy;
        const float dist = sqrtf(dx * dx + dy * dy);
        const float m = (valid && dist <= RADIUS) ? 1.0f : 0.0f;
        cnt += m;

        float r = fminf(dist * rhinv, 1.0f);
        int idx = (int)(r * (float)(KNOTS - 1));
        idx = idx > (KNOTS - 2) ? (KNOTS - 2) : idx;
        const float tk  = (float)idx * (1.0f / (float)(KNOTS - 1));
        const float tk1 = (idx == KNOTS - 2) ? 1.0f
                        : (float)(idx + 1) * (1.0f / (float)(KNOTS - 1));
        const float wr  = (r - tk) / (tk1 - tk + EPS_T);
        const float psi = (1.0f - wr) * s_Sm[wv][idx] + wr * s_Sm[wv][idx + 1];

        pw[s]   = psi * m;
        xjv[s]  = xx;
        yjv[s]  = yy;
        accp[s] = b2;
    }

    // neighbor count -> 1/norm on every lane
    #pragma unroll
    for (int m = 1; m < 64; m <<= 1) cnt += __shfl_xor(cnt, m, 64);
    const float rnorm = 1.0f / fmaxf(cnt, 1.0f);

    // phi MLP, loop-swapped: one broadcast ds_read_b128 serves 6 candidates
    #pragma unroll
    for (int k = 0; k < 32; ++k) {
        const float4 q = s_pq[wv][k];
        #pragma unroll
        for (int s = 0; s < NCAND; ++s) {
            const float hk = fmaf(xjv[s], q.y, fmaf(yjv[s], q.z, q.x));
            accp[s] = fmaf(fmaxf(hk, 0.0f), q.w, accp[s]);
        }
    }

    #pragma unroll
    for (int s = 0; s < NCAND; ++s) {
        const int t = lane + 64 * s;
        if (t < WIN2) s_w[wv][t] = accp[s] * pw[s] * rnorm;
    }

    wave_lds_fence();

    // ---- Phase B: 8 reps x (2 batches x 4-channel groups); direct addressing
    const int rep = lane >> 3;
    const int pc  = lane & 7;
    const int b   = pc >> 2;
    const int c4  = pc & 3;
    const float* xb = x + b * NP * CH + c4 * 4;

    float4 acc = make_float4(0.0f, 0.0f, 0.0f, 0.0f);
    int t = rep, a = 0, bb = rep;
    #pragma unroll 8
    for (int n = 0; n < 46; ++n) {
        if (t < WIN2) {
            const int rj  = ri + a - 9;
            const int cj  = ci + bb - 9;
            const int rjc = min(max(rj, 0), HG - 1);
            const int cjc = min(max(cj, 0), HG - 1);
            const int j   = rjc * HG + cjc;
            const float wgt = s_w[wv][t];
            const float4 xv = *(const float4*)(xb + j * CH);
            acc.x = fmaf(wgt, xv.x, acc.x);
            acc.y = fmaf(wgt, xv.y, acc.y);
            acc.z = fmaf(wgt, xv.z, acc.z);
            acc.w = fmaf(wgt, xv.w, acc.w);
        }
        t += 8;
        bb += 8;
        const int ov = (bb >= WIN) ? 1 : 0;
        bb -= ov * WIN;
        a  += ov;
    }

    #pragma unroll
    for (int off = 8; off < 64; off <<= 1) {
        acc.x += __shfl_down(acc.x, off, 64);
        acc.y += __shfl_down(acc.y, off, 64);
        acc.z += __shfl_down(acc.z, off, 64);
        acc.w += __shfl_down(acc.w, off, 64);
    }

    if (rep == 0) {
        *(float4*)(out + (size_t)(b * NP + i) * CH + c4 * 4) = acc;
    }
}

extern "C" void kernel_launch(void* const* d_in, const int* in_sizes, int n_in,
                              void* d_out, int out_size, void* d_ws, size_t ws_size,
                              hipStream_t stream) {
    const float* x      = (const float*)d_in[0];
    const float* phi_w1 = (const float*)d_in[1];
    const float* phi_b1 = (const float*)d_in[2];
    const float* phi_w2 = (const float*)d_in[3];
    const float* phi_b2 = (const float*)d_in[4];
    const float* h_w1   = (const float*)d_in[5];
    const float* h_b1   = (const float*)d_in[6];
    const float* h_w2   = (const float*)d_in[7];
    const float* h_b2   = (const float*)d_in[8];
    const float* S_m    = (const float*)d_in[9];
    float* out          = (float*)d_out;

    si_blocks_kernel<<<dim3(NP / PPB), dim3(256), 0, stream>>>(
        x, phi_w1, phi_b1, phi_w2, phi_b2,
        h_w1, h_b1, h_w2, h_b2, S_m, out);
}

// Round 4
// 83.670 us; speedup vs baseline: 1.0611x; 1.0611x over previous
//
#include <hip/hip_runtime.h>
#include <cmath>

namespace {
constexpr int HG = 48;
constexpr int NP = HG * HG;        // 2304
constexpr int CH = 16;
constexpr int WIN = 19;            // offsets -9..9
constexpr int WIN2 = WIN * WIN;    // 361
constexpr float RADIUS = 0.2f;
constexpr float EPS_H = 1e-6f;
constexpr float EPS_T = 1e-8f;
constexpr int KNOTS = 16;
}

__device__ __forceinline__ float lin48(int t) {
    return (t == HG - 1) ? 1.0f : (float)t * (1.0f / 47.0f);
}

__device__ __forceinline__ float softplus_f(float v) {
    return fmaxf(v, 0.0f) + log1pf(expf(-fabsf(v)));
}

// block = one query point, 256 threads (4 waves); grid = 2304
__global__ __launch_bounds__(256)
void si_blocks_kernel(const float* __restrict__ x,
                      const float* __restrict__ phi_w1,
                      const float* __restrict__ phi_b1,
                      const float* __restrict__ phi_w2,
                      const float* __restrict__ phi_b2,
                      const float* __restrict__ h_w1,
                      const float* __restrict__ h_b1,
                      const float* __restrict__ h_w2,
                      const float* __restrict__ h_b2,
                      const float* __restrict__ S_m,
                      float* __restrict__ out)
{
    const int tid  = threadIdx.x;
    const int lane = tid & 63;
    const int wv   = tid >> 6;
    const int i    = blockIdx.x;
    const int ri   = i / HG;
    const int ci   = i - ri * HG;
    const float xi = lin48(ri);
    const float yi = lin48(ci);

    __shared__ float4 s_pq[32];        // (pre_k, wx_k, wy_k, w2_k)
    __shared__ float  s_Sm[KNOTS];
    __shared__ float  s_w[WIN2];       // unnormalized weights
    __shared__ float4 s_part[4][8];
    __shared__ float  s_cnt[4];

    if (tid < 32) {
        const float pre = xi * phi_w1[tid] + yi * phi_w1[32 + tid] + phi_b1[tid];
        s_pq[tid] = make_float4(pre, phi_w1[64 + tid], phi_w1[96 + tid], phi_w2[tid]);
    } else if (tid < 32 + KNOTS) {
        s_Sm[tid - 32] = S_m[tid - 32];
    }

    // h_net: each wave computes redundantly; 32-lane xor reduce in both halves
    float hval;
    {
        const int k = lane & 31;
        float t = fmaxf(xi * h_w1[k] + yi * h_w1[32 + k] + h_b1[k], 0.0f) * h_w2[k];
        #pragma unroll
        for (int m = 1; m < 32; m <<= 1) t += __shfl_xor(t, m, 64);
        hval = softplus_f(t + h_b2[0]) + EPS_H;
    }
    const float rhinv = 1.0f / hval;
    const float b2    = phi_b2[0];

    __syncthreads();

    // ---- Phase A: 361 candidates, <=2 per thread (t = tid, tid+256)
    float cnt = 0.0f;
    #pragma unroll
    for (int s = 0; s < 2; ++s) {
        const int t  = tid + 256 * s;
        const bool in = (t < WIN2);
        const int tt = in ? t : 0;
        const int a  = tt / WIN;
        const int bb = tt - a * WIN;
        const int rj = ri + a - 9;
        const int cj = ci + bb - 9;
        const bool valid = in && ((unsigned)rj < (unsigned)HG) &&
                                 ((unsigned)cj < (unsigned)HG);
        const int rjc = min(max(rj, 0), HG - 1);
        const int cjc = min(max(cj, 0), HG - 1);
        const float xx = lin48(rjc);
        const float yy = lin48(cjc);
        const float dx = xi - xx;
        const float dy = yi - yy;
        const float dist = sqrtf(dx * dx + dy * dy);
        const bool hit = valid && (dist <= RADIUS);

        // neighbor count via ballot (all 64 lanes participate)
        const unsigned long long bal = __ballot(hit);
        cnt = fmaf(1.0f, (float)__popcll(bal), cnt);   // same for all lanes

        // radial spline
        float r = fminf(dist * rhinv, 1.0f);
        int idx = (int)(r * (float)(KNOTS - 1));
        idx = idx > (KNOTS - 2) ? (KNOTS - 2) : idx;
        const float tk  = (float)idx * (1.0f / (float)(KNOTS - 1));
        const float tk1 = (idx == KNOTS - 2) ? 1.0f
                        : (float)(idx + 1) * (1.0f / (float)(KNOTS - 1));
        const float wr  = (r - tk) / (tk1 - tk + EPS_T);
        const float psi = (1.0f - wr) * s_Sm[idx] + wr * s_Sm[idx + 1];

        // phi MLP: 2 partial accumulators to halve the dependent-FMA chain
        float p0 = b2, p1 = 0.0f;
        #pragma unroll
        for (int k = 0; k < 32; k += 2) {
            const float4 q0 = s_pq[k];
            const float4 q1 = s_pq[k + 1];
            const float h0 = fmaf(xx, q0.y, fmaf(yy, q0.z, q0.x));
            const float h1 = fmaf(xx, q1.y, fmaf(yy, q1.z, q1.x));
            p0 = fmaf(fmaxf(h0, 0.0f), q0.w, p0);
            p1 = fmaf(fmaxf(h1, 0.0f), q1.w, p1);
        }
        if (in) s_w[t] = hit ? (p0 + p1) * psi : 0.0f;
    }
    if (lane == 0) s_cnt[wv] = cnt;    // cnt identical across the wave

    __syncthreads();

    // ---- Phase B: 32 reps (4 waves x 8) x (2 batches x 4-chan groups)
    const int rep   = lane >> 3;           // 0..7
    const int rep32 = wv * 8 + rep;        // 0..31
    const int pc    = lane & 7;
    const int b     = pc >> 2;
    const int c4    = pc & 3;
    const float* xb = x + b * NP * CH + c4 * 4;

    float4 acc = make_float4(0.0f, 0.0f, 0.0f, 0.0f);
    int t  = rep32;
    int a  = (rep32 >= WIN) ? 1 : 0;
    int bb = rep32 - a * WIN;
    #pragma unroll
    for (int n = 0; n < 12; ++n) {
        if (t < WIN2) {
            const int rjc = min(max(ri + a - 9, 0), HG - 1);
            const int cjc = min(max(ci + bb - 9, 0), HG - 1);
            const int j   = rjc * HG + cjc;
            const float wgt = s_w[t];
            const float4 xv = *(const float4*)(xb + j * CH);
            acc.x = fmaf(wgt, xv.x, acc.x);
            acc.y = fmaf(wgt, xv.y, acc.y);
            acc.z = fmaf(wgt, xv.z, acc.z);
            acc.w = fmaf(wgt, xv.w, acc.w);
        }
        t += 32;
        bb += 13; a += 1;                  // += 32 in (a,bb) space
        if (bb >= WIN) { bb -= WIN; a += 1; }
    }

    #pragma unroll
    for (int off = 8; off < 64; off <<= 1) {
        acc.x += __shfl_down(acc.x, off, 64);
        acc.y += __shfl_down(acc.y, off, 64);
        acc.z += __shfl_down(acc.z, off, 64);
        acc.w += __shfl_down(acc.w, off, 64);
    }
    if (rep == 0) s_part[wv][pc] = acc;

    __syncthreads();

    if (tid < 8) {
        const float4 a0 = s_part[0][tid];
        const float4 a1 = s_part[1][tid];
        const float4 a2 = s_part[2][tid];
        const float4 a3 = s_part[3][tid];
        const float ctot = s_cnt[0] + s_cnt[1] + s_cnt[2] + s_cnt[3];
        const float rnorm = 1.0f / fmaxf(ctot, 1.0f);
        float4 r;
        r.x = (a0.x + a1.x + a2.x + a3.x) * rnorm;
        r.y = (a0.y + a1.y + a2.y + a3.y) * rnorm;
        r.z = (a0.z + a1.z + a2.z + a3.z) * rnorm;
        r.w = (a0.w + a1.w + a2.w + a3.w) * rnorm;
        const int bo = tid >> 2;
        const int co = tid & 3;
        *(float4*)(out + (size_t)(bo * NP + i) * CH + co * 4) = r;
    }
}

extern "C" void kernel_launch(void* const* d_in, const int* in_sizes, int n_in,
                              void* d_out, int out_size, void* d_ws, size_t ws_size,
                              hipStream_t stream) {
    const float* x      = (const float*)d_in[0];
    const float* phi_w1 = (const float*)d_in[1];
    const float* phi_b1 = (const float*)d_in[2];
    const float* phi_w2 = (const float*)d_in[3];
    const float* phi_b2 = (const float*)d_in[4];
    const float* h_w1   = (const float*)d_in[5];
    const float* h_b1   = (const float*)d_in[6];
    const float* h_w2   = (const float*)d_in[7];
    const float* h_b2   = (const float*)d_in[8];
    const float* S_m    = (const float*)d_in[9];
    float* out          = (float*)d_out;

    si_blocks_kernel<<<dim3(NP), dim3(256), 0, stream>>>(
        x, phi_w1, phi_b1, phi_w2, phi_b2,
        h_w1, h_b1, h_w2, h_b2, S_m, out);
}